// Round 8
// baseline (736.461 us; speedup 1.0000x reference)
//
#include <hip/hip_runtime.h>
#include <hip/hip_bf16.h>

#define N_NODES 50000
#define N_EDGES 800000
#define D_FEAT 64

#define NBUCK 196                 // ceil(50000/256) buckets of 256 dst nodes
#define CHUNK 8192                // edges per partition block
#define NB ((N_EDGES + CHUNK - 1) / CHUNK)   // 98
#define NT (NBUCK * NB)           // 19208 (bucket-major count matrix)
#define SCH ((NT + 1023) / 1024)  // 19 elems per thread in flat scan

// ---- bf16 helpers (manual, RNE) ----
__device__ __forceinline__ unsigned short f2b(float f) {
    unsigned int u = __float_as_uint(f);
    unsigned int lsb = (u >> 16) & 1u;
    u += 0x7fffu + lsb;
    return (unsigned short)(u >> 16);
}
__device__ __forceinline__ float blo(unsigned int u) { return __uint_as_float(u << 16); }
__device__ __forceinline__ float bhi(unsigned int u) { return __uint_as_float(u & 0xffff0000u); }

// ---------- x -> bf16 table ----------
__global__ void cvt_kernel(const float* __restrict__ x, unsigned short* __restrict__ xb) {
    int i = blockIdx.x * blockDim.x + threadIdx.x;
    if (i >= (N_NODES * D_FEAT) / 4) return;
    float4 v = reinterpret_cast<const float4*>(x)[i];
    ushort4 o;
    o.x = f2b(v.x); o.y = f2b(v.y); o.z = f2b(v.z); o.w = f2b(v.w);
    reinterpret_cast<ushort4*>(xb)[i] = o;
}

// ---------- partition stage 1: per-(bucket,block) histogram ----------
__global__ __launch_bounds__(1024) void hist_part_kernel(const int* __restrict__ dst,
                                                         int* __restrict__ counts) {
    __shared__ int h[NBUCK];
    int t = threadIdx.x, blk = blockIdx.x;
    for (int i = t; i < NBUCK; i += 1024) h[i] = 0;
    __syncthreads();
    int e0 = blk * CHUNK;
    int ce = min(CHUNK, N_EDGES - e0);
    for (int k = 0; k < CHUNK / 1024; ++k) {
        int i = t + k * 1024;
        if (i < ce) atomicAdd(&h[dst[e0 + i] >> 8], 1);
    }
    __syncthreads();
    for (int i = t; i < NBUCK; i += 1024) counts[i * NB + blk] = h[i];  // bucket-major
}

// ---------- partition stage 2: flat exclusive scan of counts[NT] ----------
// Bucket-major order makes offs[b*NB+blk] the exact global write base of
// segment (bucket b, block blk).
__global__ __launch_bounds__(1024) void scan_flat_kernel(const int* __restrict__ counts,
                                                         int* __restrict__ offs) {
    __shared__ int part[1024];
    int t = threadIdx.x;
    int base = t * SCH;
    int loc[SCH];
    int s = 0;
    for (int i = 0; i < SCH; ++i) {
        int idx = base + i;
        int v = (idx < NT) ? counts[idx] : 0;
        loc[i] = s;
        s += v;
    }
    part[t] = s;
    __syncthreads();
    for (int off = 1; off < 1024; off <<= 1) {
        int v = (t >= off) ? part[t - off] : 0;
        __syncthreads();
        part[t] += v;
        __syncthreads();
    }
    int run = (t == 0) ? 0 : part[t - 1];
    for (int i = 0; i < SCH; ++i) {
        int idx = base + i;
        if (idx < NT) offs[idx] = run + loc[i];
    }
    if (t == 1023) offs[NT] = part[1023];  // = N_EDGES
}

// ---------- partition stage 3: LDS reorder + coalesced write-out ----------
__global__ __launch_bounds__(1024) void partition_kernel(const int* __restrict__ src,
                                                         const int* __restrict__ dst,
                                                         const float* __restrict__ val,
                                                         const int* __restrict__ offs,
                                                         int2* __restrict__ pack) {
    __shared__ int2 stag[CHUNK];     // 64 KB staging
    __shared__ int  hist[NBUCK];
    __shared__ int  basearr[256];    // padded, nondecreasing
    __shared__ int  cur[NBUCK];
    __shared__ int  sboff[NBUCK];
    __shared__ int  sc[256];
    int t = threadIdx.x, blk = blockIdx.x;
    int e0 = blk * CHUNK;
    int ce = min(CHUNK, N_EDGES - e0);

    for (int i = t; i < NBUCK; i += 1024) hist[i] = 0;
    __syncthreads();
    for (int k = 0; k < CHUNK / 1024; ++k) {
        int i = t + k * 1024;
        if (i < ce) atomicAdd(&hist[dst[e0 + i] >> 8], 1);
    }
    __syncthreads();
    if (t < 256) sc[t] = (t < NBUCK) ? hist[t] : 0;
    __syncthreads();
    for (int off = 1; off < 256; off <<= 1) {
        int v = 0;
        if (t < 256 && t >= off) v = sc[t - off];
        __syncthreads();
        if (t < 256) sc[t] += v;
        __syncthreads();
    }
    if (t < 256) {
        int excl = (t < NBUCK) ? (sc[t] - hist[t]) : ce;
        basearr[t] = excl;
        if (t < NBUCK) {
            cur[t]   = excl;
            sboff[t] = offs[t * NB + blk];
        }
    }
    __syncthreads();
    for (int k = 0; k < CHUNK / 1024; ++k) {
        int i = t + k * 1024;
        if (i < ce) {
            int e = e0 + i;
            int d = dst[e];
            int b = d >> 8;
            int slot = atomicAdd(&cur[b], 1);
            stag[slot] = make_int2((src[e] & 0xffff) | ((d & 255) << 16),
                                   __float_as_int(val[e]));
        }
    }
    __syncthreads();
    for (int k = 0; k < CHUNK / 1024; ++k) {
        int i = t + k * 1024;
        if (i < ce) {
            // largest b with basearr[b] <= i  (basearr[0]=0, pads = ce > i)
            int lo = 0, hi = 255;
            for (int s8 = 0; s8 < 8; ++s8) {
                int mid = (lo + hi + 1) >> 1;
                if (basearr[mid] <= i) lo = mid; else hi = mid - 1;
            }
            pack[sboff[lo] + (i - basearr[lo])] = stag[i];  // coalesced runs
        }
    }
}

// ---------- hop 1: bucket-block SpMM, LDS fp32 accumulate, bf16 out ----------
__global__ __launch_bounds__(1024) void hop1_kernel(const int* __restrict__ offs,
                                                    const int2* __restrict__ pack,
                                                    const unsigned short* __restrict__ xb,
                                                    unsigned short* __restrict__ hb) {
    __shared__ float acc[256 * 65];  // +1 row pad -> conflict-light
    int t = threadIdx.x, bucket = blockIdx.x;
    for (int k = 0; k < 17; ++k) {
        int i = t + k * 1024;
        if (i < 256 * 65) acc[i] = 0.f;
    }
    __syncthreads();
    int es = offs[bucket * NB], ee = offs[(bucket + 1) * NB];
    int lane = t & 31, eslot = t >> 5;
    const unsigned short* xbl = xb + lane * 2;
    int i = es + eslot;
    for (; i + 32 < ee; i += 64) {
        int2 p0 = pack[i], p1 = pack[i + 32];
        int s0 = p0.x & 0xffff, d0 = (p0.x >> 16) & 0xff;
        int s1 = p1.x & 0xffff, d1 = (p1.x >> 16) & 0xff;
        float v0 = __int_as_float(p0.y), v1 = __int_as_float(p1.y);
        unsigned u0 = *reinterpret_cast<const unsigned*>(xbl + s0 * D_FEAT);
        unsigned u1 = *reinterpret_cast<const unsigned*>(xbl + s1 * D_FEAT);
        atomicAdd(&acc[d0 * 65 + lane * 2],     v0 * blo(u0));
        atomicAdd(&acc[d0 * 65 + lane * 2 + 1], v0 * bhi(u0));
        atomicAdd(&acc[d1 * 65 + lane * 2],     v1 * blo(u1));
        atomicAdd(&acc[d1 * 65 + lane * 2 + 1], v1 * bhi(u1));
    }
    if (i < ee) {
        int2 p0 = pack[i];
        int s0 = p0.x & 0xffff, d0 = (p0.x >> 16) & 0xff;
        float v0 = __int_as_float(p0.y);
        unsigned u0 = *reinterpret_cast<const unsigned*>(xbl + s0 * D_FEAT);
        atomicAdd(&acc[d0 * 65 + lane * 2],     v0 * blo(u0));
        atomicAdd(&acc[d0 * 65 + lane * 2 + 1], v0 * bhi(u0));
    }
    __syncthreads();
    int nodebase = bucket << 8;
    unsigned* hbw = reinterpret_cast<unsigned*>(hb);
    for (int k = 0; k < 8; ++k) {
        int u2 = t + k * 1024;          // 0..8191 uints = 256 rows x 32
        int node = u2 >> 5, w = u2 & 31;
        if (nodebase + node < N_NODES) {
            float f0 = acc[node * 65 + 2 * w], f1 = acc[node * 65 + 2 * w + 1];
            hbw[((long)nodebase << 5) + u2] = (unsigned)f2b(f0) | ((unsigned)f2b(f1) << 16);
        }
    }
}

// ---------- hop 2 + FC + log_softmax fused ----------
__global__ __launch_bounds__(1024) void hop2_fc_kernel(const int* __restrict__ offs,
                                                       const int2* __restrict__ pack,
                                                       const unsigned short* __restrict__ hbsrc,
                                                       const float* __restrict__ w,
                                                       const float* __restrict__ b,
                                                       float* __restrict__ out) {
    __shared__ float acc[256 * 65];
    int t = threadIdx.x, bucket = blockIdx.x;
    for (int k = 0; k < 17; ++k) {
        int i = t + k * 1024;
        if (i < 256 * 65) acc[i] = 0.f;
    }
    __syncthreads();
    int es = offs[bucket * NB], ee = offs[(bucket + 1) * NB];
    int lane = t & 31, eslot = t >> 5;
    const unsigned short* hbl = hbsrc + lane * 2;
    int i = es + eslot;
    for (; i + 32 < ee; i += 64) {
        int2 p0 = pack[i], p1 = pack[i + 32];
        int s0 = p0.x & 0xffff, d0 = (p0.x >> 16) & 0xff;
        int s1 = p1.x & 0xffff, d1 = (p1.x >> 16) & 0xff;
        float v0 = __int_as_float(p0.y), v1 = __int_as_float(p1.y);
        unsigned u0 = *reinterpret_cast<const unsigned*>(hbl + s0 * D_FEAT);
        unsigned u1 = *reinterpret_cast<const unsigned*>(hbl + s1 * D_FEAT);
        atomicAdd(&acc[d0 * 65 + lane * 2],     v0 * blo(u0));
        atomicAdd(&acc[d0 * 65 + lane * 2 + 1], v0 * bhi(u0));
        atomicAdd(&acc[d1 * 65 + lane * 2],     v1 * blo(u1));
        atomicAdd(&acc[d1 * 65 + lane * 2 + 1], v1 * bhi(u1));
    }
    if (i < ee) {
        int2 p0 = pack[i];
        int s0 = p0.x & 0xffff, d0 = (p0.x >> 16) & 0xff;
        float v0 = __int_as_float(p0.y);
        unsigned u0 = *reinterpret_cast<const unsigned*>(hbl + s0 * D_FEAT);
        atomicAdd(&acc[d0 * 65 + lane * 2],     v0 * blo(u0));
        atomicAdd(&acc[d0 * 65 + lane * 2 + 1], v0 * bhi(u0));
    }
    __syncthreads();
    // FC + log_softmax: 4 lanes per node
    int node = t >> 2, j = t & 3;
    int g = (bucket << 8) + node;
    if (g < N_NODES) {
        float p0 = 0.f, p1 = 0.f;
        const float* w0 = w + j * 16;
        const float* w1 = w + D_FEAT + j * 16;
#pragma unroll
        for (int q = 0; q < 16; ++q) {
            float f = acc[node * 65 + j * 16 + q];
            p0 += f * w0[q];
            p1 += f * w1[q];
        }
        p0 += __shfl_down(p0, 2, 4); p0 += __shfl_down(p0, 1, 4);
        p1 += __shfl_down(p1, 2, 4); p1 += __shfl_down(p1, 1, 4);
        if (j == 0) {
            float a0 = p0 + b[0], a1 = p1 + b[1];
            float m = fmaxf(a0, a1);
            float lse = m + logf(expf(a0 - m) + expf(a1 - m));
            out[(long)g * 2 + 0] = a0 - lse;
            out[(long)g * 2 + 1] = a1 - lse;
        }
    }
}

extern "C" void kernel_launch(void* const* d_in, const int* in_sizes, int n_in,
                              void* d_out, int out_size, void* d_ws, size_t ws_size,
                              hipStream_t stream) {
    const float* x        = (const float*)d_in[0];
    const int*   edge_src = (const int*)d_in[1];
    const int*   edge_dst = (const int*)d_in[2];
    const float* edge_val = (const float*)d_in[3];
    const float* fc_w     = (const float*)d_in[4];
    const float* fc_b     = (const float*)d_in[5];
    float* out = (float*)d_out;

    const size_t tab_elems = (size_t)N_NODES * D_FEAT;  // 3.2M
    unsigned short* xb     = (unsigned short*)d_ws;          // 6.4 MB
    unsigned short* hb     = xb + tab_elems;                 // 6.4 MB
    int2*           pack   = (int2*)(hb + tab_elems);        // 6.4 MB
    int*            counts = (int*)(pack + N_EDGES);         // NT ints
    int*            offs   = counts + NT;                    // NT+1 ints
    // total ~= 19.4 MB

    // ---- bf16 conversion + edge partition ----
    cvt_kernel<<<((N_NODES * D_FEAT / 4) + 255) / 256, 256, 0, stream>>>(x, xb);
    hist_part_kernel<<<NB, 1024, 0, stream>>>(edge_dst, counts);
    scan_flat_kernel<<<1, 1024, 0, stream>>>(counts, offs);
    partition_kernel<<<NB, 1024, 0, stream>>>(edge_src, edge_dst, edge_val, offs, pack);

    // ---- hop 1 (bucket-block, LDS accumulate) ----
    hop1_kernel<<<NBUCK, 1024, 0, stream>>>(offs, pack, xb, hb);

    // ---- hop 2 + fc + log_softmax (fused) ----
    hop2_fc_kernel<<<NBUCK, 1024, 0, stream>>>(offs, pack, hb, fc_w, fc_b, out);
}

// Round 10
// 74.200 us; speedup vs baseline: 9.9254x; 9.9254x over previous
//
#include <hip/hip_runtime.h>
#include <hip/hip_bf16.h>

#define N_NODES 50000
#define N_EDGES 800000
#define D_FEAT 64

#define NBUCK 196                 // buckets of 256 dst nodes
#define CHUNK 8192                // edges per level-1 block
#define NB ((N_EDGES + CHUNK - 1) / CHUNK)   // 98
#define NT (NBUCK * NB)           // 19208 (bucket-major count matrix)
#define NPB ((NT + 255) / 256)    // 76 blocks for the count scan
#define BSTAG 6144                // per-bucket staging capacity (mean 4096, sd 64)

// ---- bf16 helpers (manual, RNE) ----
__device__ __forceinline__ unsigned short f2b(float f) {
    unsigned int u = __float_as_uint(f);
    unsigned int lsb = (u >> 16) & 1u;
    u += 0x7fffu + lsb;
    return (unsigned short)(u >> 16);
}
__device__ __forceinline__ float blo(unsigned int u) { return __uint_as_float(u << 16); }
__device__ __forceinline__ float bhi(unsigned int u) { return __uint_as_float(u & 0xffff0000u); }

// ---------- x -> bf16 table ----------
__global__ void cvt_kernel(const float* __restrict__ x, unsigned short* __restrict__ xb) {
    int i = blockIdx.x * blockDim.x + threadIdx.x;
    if (i >= (N_NODES * D_FEAT) / 4) return;
    float4 v = reinterpret_cast<const float4*>(x)[i];
    ushort4 o;
    o.x = f2b(v.x); o.y = f2b(v.y); o.z = f2b(v.z); o.w = f2b(v.w);
    reinterpret_cast<ushort4*>(xb)[i] = o;
}

// ---------- level 1 stage 1: per-(bucket,block) histogram ----------
__global__ __launch_bounds__(1024) void hist_part_kernel(const int* __restrict__ dst,
                                                         int* __restrict__ counts) {
    __shared__ int h[NBUCK];
    int t = threadIdx.x, blk = blockIdx.x;
    for (int i = t; i < NBUCK; i += 1024) h[i] = 0;
    __syncthreads();
    int e0 = blk * CHUNK;
    int ce = min(CHUNK, N_EDGES - e0);
    for (int k = 0; k < CHUNK / 1024; ++k) {
        int i = t + k * 1024;
        if (i < ce) atomicAdd(&h[dst[e0 + i] >> 8], 1);
    }
    __syncthreads();
    for (int i = t; i < NBUCK; i += 1024) counts[i * NB + blk] = h[i];  // bucket-major
}

// ---------- level 1 stage 2: two-level scan of counts[NT] ----------
__global__ void scanA_block_kernel(const int* __restrict__ counts,
                                   int* __restrict__ pre,
                                   int* __restrict__ partials) {
    __shared__ int sm[256];
    int i = blockIdx.x * 256 + threadIdx.x;
    int v = (i < NT) ? counts[i] : 0;
    sm[threadIdx.x] = v;
    __syncthreads();
    for (int off = 1; off < 256; off <<= 1) {
        int t2 = (threadIdx.x >= (unsigned)off) ? sm[threadIdx.x - off] : 0;
        __syncthreads();
        sm[threadIdx.x] += t2;
        __syncthreads();
    }
    if (i < NT) pre[i] = sm[threadIdx.x] - v;
    if (threadIdx.x == 255) partials[blockIdx.x] = sm[threadIdx.x];
}

__global__ void scanA_partials_kernel(const int* __restrict__ partials,
                                      int* __restrict__ boffs) {
    __shared__ int sm[256];
    int t = threadIdx.x;
    int v = (t < NPB) ? partials[t] : 0;
    sm[t] = v;
    __syncthreads();
    for (int off = 1; off < 256; off <<= 1) {
        int u = (t >= off) ? sm[t - off] : 0;
        __syncthreads();
        sm[t] += u;
        __syncthreads();
    }
    if (t < NPB) boffs[t] = sm[t] - v;
}

__global__ void scanA_final_kernel(const int* __restrict__ pre,
                                   const int* __restrict__ boffs,
                                   int* __restrict__ offs) {
    int i = blockIdx.x * 256 + threadIdx.x;
    if (i < NT) offs[i] = pre[i] + boffs[blockIdx.x];
    if (i == 0) offs[NT] = N_EDGES;
}

// ---------- level 1 stage 3: LDS reorder + coalesced write-out ----------
__global__ __launch_bounds__(1024) void partition_kernel(const int* __restrict__ src,
                                                         const int* __restrict__ dst,
                                                         const float* __restrict__ val,
                                                         const int* __restrict__ offs,
                                                         int2* __restrict__ pack) {
    __shared__ int2 stag[CHUNK];     // 64 KB staging
    __shared__ int  hist[NBUCK];
    __shared__ int  basearr[256];
    __shared__ int  cur[NBUCK];
    __shared__ int  sboff[NBUCK];
    __shared__ int  sc[256];
    int t = threadIdx.x, blk = blockIdx.x;
    int e0 = blk * CHUNK;
    int ce = min(CHUNK, N_EDGES - e0);

    for (int i = t; i < NBUCK; i += 1024) hist[i] = 0;
    __syncthreads();
    for (int k = 0; k < CHUNK / 1024; ++k) {
        int i = t + k * 1024;
        if (i < ce) atomicAdd(&hist[dst[e0 + i] >> 8], 1);
    }
    __syncthreads();
    if (t < 256) sc[t] = (t < NBUCK) ? hist[t] : 0;
    __syncthreads();
    for (int off = 1; off < 256; off <<= 1) {
        int v = 0;
        if (t < 256 && t >= off) v = sc[t - off];
        __syncthreads();
        if (t < 256) sc[t] += v;
        __syncthreads();
    }
    if (t < 256) {
        int excl = (t < NBUCK) ? (sc[t] - hist[t]) : ce;
        basearr[t] = excl;
        if (t < NBUCK) {
            cur[t]   = excl;
            sboff[t] = offs[t * NB + blk];
        }
    }
    __syncthreads();
    for (int k = 0; k < CHUNK / 1024; ++k) {
        int i = t + k * 1024;
        if (i < ce) {
            int e = e0 + i;
            int d = dst[e];
            int b = d >> 8;
            int slot = atomicAdd(&cur[b], 1);
            stag[slot] = make_int2((src[e] & 0xffff) | ((d & 255) << 16),
                                   __float_as_int(val[e]));
        }
    }
    __syncthreads();
    for (int k = 0; k < CHUNK / 1024; ++k) {
        int i = t + k * 1024;
        if (i < ce) {
            int lo = 0, hi = 255;
            for (int s8 = 0; s8 < 8; ++s8) {
                int mid = (lo + hi + 1) >> 1;
                if (basearr[mid] <= i) lo = mid; else hi = mid - 1;
            }
            pack[sboff[lo] + (i - basearr[lo])] = stag[i];  // coalesced runs
        }
    }
}

// ---------- level 2: per-bucket LDS counting sort (in place) + row_ptr ----------
__global__ __launch_bounds__(1024) void bucket_sort_kernel(const int* __restrict__ offs,
                                                           int2* __restrict__ pack,
                                                           int* __restrict__ row_ptr) {
    __shared__ int2 stag[BSTAG];     // 48 KB
    __shared__ int2 sorted[BSTAG];   // 48 KB
    __shared__ int  cnt[256];
    __shared__ int  sc[256];
    __shared__ int  cur[256];
    int t = threadIdx.x, b = blockIdx.x;
    int es = offs[b * NB];
    int ee = (b == NBUCK - 1) ? N_EDGES : offs[(b + 1) * NB];
    int ce = min(ee - es, BSTAG);

    if (t < 256) cnt[t] = 0;
    __syncthreads();
    for (int k = 0; k < BSTAG / 1024; ++k) {
        int i = t + k * 1024;
        if (i < ce) {
            int2 p = pack[es + i];
            stag[i] = p;
            atomicAdd(&cnt[(p.x >> 16) & 255], 1);
        }
    }
    __syncthreads();
    if (t < 256) sc[t] = cnt[t];
    __syncthreads();
    for (int off = 1; off < 256; off <<= 1) {
        int v = 0;
        if (t < 256 && t >= off) v = sc[t - off];
        __syncthreads();
        if (t < 256) sc[t] += v;
        __syncthreads();
    }
    if (t < 256) {
        int excl = sc[t] - cnt[t];
        cur[t] = excl;
        int node = (b << 8) + t;
        if (node < N_NODES) row_ptr[node] = es + excl;
        if (b == NBUCK - 1 && t == 0) row_ptr[N_NODES] = N_EDGES;
    }
    __syncthreads();
    for (int k = 0; k < BSTAG / 1024; ++k) {
        int i = t + k * 1024;
        if (i < ce) {
            int2 p = stag[i];
            int d = (p.x >> 16) & 255;
            int slot = atomicAdd(&cur[d], 1);
            sorted[slot] = make_int2(p.x & 0xffff, p.y);  // {src, f32 val}
        }
    }
    __syncthreads();
    for (int k = 0; k < BSTAG / 1024; ++k) {
        int i = t + k * 1024;
        if (i < ce) pack[es + i] = sorted[i];  // coalesced in-place write-back
    }
}

// ---------- hop 1: gather SpMM, bf16 in -> bf16 out ----------
// 8 lanes per node, 8 feats (16B uint4) per lane; 4 gathers in flight.
__global__ void spmm_gather_kernel(const int* __restrict__ row_ptr,
                                   const int2* __restrict__ pack,
                                   const unsigned short* __restrict__ xb,
                                   unsigned short* __restrict__ hb) {
    int t = blockIdx.x * blockDim.x + threadIdx.x;
    int node = t >> 3;
    if (node >= N_NODES) return;
    int c = (t & 7) << 3;
    int beg = row_ptr[node];
    int end = row_ptr[node + 1];
    float a0 = 0.f, a1 = 0.f, a2 = 0.f, a3 = 0.f, a4 = 0.f, a5 = 0.f, a6 = 0.f, a7 = 0.f;
    int j = beg;
    for (; j + 3 < end; j += 4) {
        int2 p0 = pack[j], p1 = pack[j + 1], p2 = pack[j + 2], p3 = pack[j + 3];
        uint4 q0 = *reinterpret_cast<const uint4*>(xb + (long)p0.x * D_FEAT + c);
        uint4 q1 = *reinterpret_cast<const uint4*>(xb + (long)p1.x * D_FEAT + c);
        uint4 q2 = *reinterpret_cast<const uint4*>(xb + (long)p2.x * D_FEAT + c);
        uint4 q3 = *reinterpret_cast<const uint4*>(xb + (long)p3.x * D_FEAT + c);
        float v0 = __int_as_float(p0.y), v1 = __int_as_float(p1.y);
        float v2 = __int_as_float(p2.y), v3 = __int_as_float(p3.y);
        a0 += v0 * blo(q0.x) + v1 * blo(q1.x) + v2 * blo(q2.x) + v3 * blo(q3.x);
        a1 += v0 * bhi(q0.x) + v1 * bhi(q1.x) + v2 * bhi(q2.x) + v3 * bhi(q3.x);
        a2 += v0 * blo(q0.y) + v1 * blo(q1.y) + v2 * blo(q2.y) + v3 * blo(q3.y);
        a3 += v0 * bhi(q0.y) + v1 * bhi(q1.y) + v2 * bhi(q2.y) + v3 * bhi(q3.y);
        a4 += v0 * blo(q0.z) + v1 * blo(q1.z) + v2 * blo(q2.z) + v3 * blo(q3.z);
        a5 += v0 * bhi(q0.z) + v1 * bhi(q1.z) + v2 * bhi(q2.z) + v3 * bhi(q3.z);
        a6 += v0 * blo(q0.w) + v1 * blo(q1.w) + v2 * blo(q2.w) + v3 * blo(q3.w);
        a7 += v0 * bhi(q0.w) + v1 * bhi(q1.w) + v2 * bhi(q2.w) + v3 * bhi(q3.w);
    }
    for (; j < end; ++j) {
        int2 p0 = pack[j];
        float v0 = __int_as_float(p0.y);
        uint4 q0 = *reinterpret_cast<const uint4*>(xb + (long)p0.x * D_FEAT + c);
        a0 += v0 * blo(q0.x); a1 += v0 * bhi(q0.x);
        a2 += v0 * blo(q0.y); a3 += v0 * bhi(q0.y);
        a4 += v0 * blo(q0.z); a5 += v0 * bhi(q0.z);
        a6 += v0 * blo(q0.w); a7 += v0 * bhi(q0.w);
    }
    uint4 o;
    o.x = (unsigned)f2b(a0) | ((unsigned)f2b(a1) << 16);
    o.y = (unsigned)f2b(a2) | ((unsigned)f2b(a3) << 16);
    o.z = (unsigned)f2b(a4) | ((unsigned)f2b(a5) << 16);
    o.w = (unsigned)f2b(a6) | ((unsigned)f2b(a7) << 16);
    *reinterpret_cast<uint4*>(hb + (long)node * D_FEAT + c) = o;
}

// ---------- hop 2 fused with FC + log_softmax ----------
__global__ void spmm_fc_fused_kernel(const int* __restrict__ row_ptr,
                                     const int2* __restrict__ pack,
                                     const unsigned short* __restrict__ hb,
                                     const float* __restrict__ w,
                                     const float* __restrict__ b,
                                     float* __restrict__ out) {
    int t = blockIdx.x * blockDim.x + threadIdx.x;
    int node = t >> 3;
    if (node >= N_NODES) return;
    int lane = t & 7;
    int c = lane << 3;
    int beg = row_ptr[node];
    int end = row_ptr[node + 1];
    float a0 = 0.f, a1 = 0.f, a2 = 0.f, a3 = 0.f, a4 = 0.f, a5 = 0.f, a6 = 0.f, a7 = 0.f;
    int j = beg;
    for (; j + 3 < end; j += 4) {
        int2 p0 = pack[j], p1 = pack[j + 1], p2 = pack[j + 2], p3 = pack[j + 3];
        uint4 q0 = *reinterpret_cast<const uint4*>(hb + (long)p0.x * D_FEAT + c);
        uint4 q1 = *reinterpret_cast<const uint4*>(hb + (long)p1.x * D_FEAT + c);
        uint4 q2 = *reinterpret_cast<const uint4*>(hb + (long)p2.x * D_FEAT + c);
        uint4 q3 = *reinterpret_cast<const uint4*>(hb + (long)p3.x * D_FEAT + c);
        float v0 = __int_as_float(p0.y), v1 = __int_as_float(p1.y);
        float v2 = __int_as_float(p2.y), v3 = __int_as_float(p3.y);
        a0 += v0 * blo(q0.x) + v1 * blo(q1.x) + v2 * blo(q2.x) + v3 * blo(q3.x);
        a1 += v0 * bhi(q0.x) + v1 * bhi(q1.x) + v2 * bhi(q2.x) + v3 * bhi(q3.x);
        a2 += v0 * blo(q0.y) + v1 * blo(q1.y) + v2 * blo(q2.y) + v3 * blo(q3.y);
        a3 += v0 * bhi(q0.y) + v1 * bhi(q1.y) + v2 * bhi(q2.y) + v3 * bhi(q3.y);
        a4 += v0 * blo(q0.z) + v1 * blo(q1.z) + v2 * blo(q2.z) + v3 * blo(q3.z);
        a5 += v0 * bhi(q0.z) + v1 * bhi(q1.z) + v2 * bhi(q2.z) + v3 * bhi(q3.z);
        a6 += v0 * blo(q0.w) + v1 * blo(q1.w) + v2 * blo(q2.w) + v3 * blo(q3.w);
        a7 += v0 * bhi(q0.w) + v1 * bhi(q1.w) + v2 * bhi(q2.w) + v3 * bhi(q3.w);
    }
    for (; j < end; ++j) {
        int2 p0 = pack[j];
        float v0 = __int_as_float(p0.y);
        uint4 q0 = *reinterpret_cast<const uint4*>(hb + (long)p0.x * D_FEAT + c);
        a0 += v0 * blo(q0.x); a1 += v0 * bhi(q0.x);
        a2 += v0 * blo(q0.y); a3 += v0 * bhi(q0.y);
        a4 += v0 * blo(q0.z); a5 += v0 * bhi(q0.z);
        a6 += v0 * blo(q0.w); a7 += v0 * bhi(q0.w);
    }
    const float4 wa0 = *reinterpret_cast<const float4*>(w + c);
    const float4 wa1 = *reinterpret_cast<const float4*>(w + c + 4);
    const float4 wb0 = *reinterpret_cast<const float4*>(w + D_FEAT + c);
    const float4 wb1 = *reinterpret_cast<const float4*>(w + D_FEAT + c + 4);
    float p0 = a0 * wa0.x + a1 * wa0.y + a2 * wa0.z + a3 * wa0.w
             + a4 * wa1.x + a5 * wa1.y + a6 * wa1.z + a7 * wa1.w;
    float p1 = a0 * wb0.x + a1 * wb0.y + a2 * wb0.z + a3 * wb0.w
             + a4 * wb1.x + a5 * wb1.y + a6 * wb1.z + a7 * wb1.w;
#pragma unroll
    for (int off = 4; off >= 1; off >>= 1) {
        p0 += __shfl_down(p0, off, 8);
        p1 += __shfl_down(p1, off, 8);
    }
    if (lane == 0) {
        float acc0 = p0 + b[0];
        float acc1 = p1 + b[1];
        float m = fmaxf(acc0, acc1);
        float lse = m + logf(expf(acc0 - m) + expf(acc1 - m));
        out[(long)node * 2 + 0] = acc0 - lse;
        out[(long)node * 2 + 1] = acc1 - lse;
    }
}

extern "C" void kernel_launch(void* const* d_in, const int* in_sizes, int n_in,
                              void* d_out, int out_size, void* d_ws, size_t ws_size,
                              hipStream_t stream) {
    const float* x        = (const float*)d_in[0];
    const int*   edge_src = (const int*)d_in[1];
    const int*   edge_dst = (const int*)d_in[2];
    const float* edge_val = (const float*)d_in[3];
    const float* fc_w     = (const float*)d_in[4];
    const float* fc_b     = (const float*)d_in[5];
    float* out = (float*)d_out;

    const size_t tab_elems = (size_t)N_NODES * D_FEAT;  // 3.2M
    unsigned short* xb      = (unsigned short*)d_ws;         // 6.4 MB
    unsigned short* hb      = xb + tab_elems;                // 6.4 MB
    int2*           pack    = (int2*)(hb + tab_elems);       // 6.4 MB
    int*            counts  = (int*)(pack + N_EDGES);        // NT
    int*            pre     = counts + NT;                   // NT
    int*            offs    = pre + NT;                      // NT+1
    int*            partials= offs + (NT + 1);               // NPB
    int*            boffs   = partials + NPB;                // NPB
    int*            row_ptr = boffs + NPB;                   // N_NODES+1
    // total ~= 19.2 MB + ~0.45 MB

    // ---- bf16 conversion + two-level counting sort ----
    cvt_kernel<<<((N_NODES * D_FEAT / 4) + 255) / 256, 256, 0, stream>>>(x, xb);
    hist_part_kernel<<<NB, 1024, 0, stream>>>(edge_dst, counts);
    scanA_block_kernel<<<NPB, 256, 0, stream>>>(counts, pre, partials);
    scanA_partials_kernel<<<1, 256, 0, stream>>>(partials, boffs);
    scanA_final_kernel<<<NPB, 256, 0, stream>>>(pre, boffs, offs);
    partition_kernel<<<NB, 1024, 0, stream>>>(edge_src, edge_dst, edge_val, offs, pack);
    bucket_sort_kernel<<<NBUCK, 1024, 0, stream>>>(offs, pack, row_ptr);

    // ---- hop 1 (bf16 -> bf16) ----
    const int threads_spmm = N_NODES * 8;
    dim3 grid_spmm((threads_spmm + 255) / 256);
    spmm_gather_kernel<<<grid_spmm, 256, 0, stream>>>(row_ptr, pack, xb, hb);

    // ---- hop 2 + fc + log_softmax (fused) ----
    spmm_fc_fused_kernel<<<grid_spmm, 256, 0, stream>>>(
        row_ptr, pack, hb, fc_w, fc_b, out);
}